// Round 9
// baseline (456.683 us; speedup 1.0000x reference)
//
#include <hip/hip_runtime.h>
#include <cstdint>

typedef unsigned short u16;
typedef unsigned long long u64;

__device__ __forceinline__ u16 f2b(float f){
  union { float f; uint32_t i; } v; v.f = f;
  uint32_t r = v.i + 0x7FFFu + ((v.i >> 16) & 1u);   // RNE
  return (u16)(r >> 16);
}
__device__ __forceinline__ float b2f(u16 u){
  union { uint32_t i; float f; } v; v.i = ((uint32_t)u) << 16; return v.f;
}
__device__ __forceinline__ float sigmoidf(float x){ return 1.0f / (1.0f + __expf(-x)); }

__device__ __forceinline__ void gl_lds4(const void* g, void* l){
  __builtin_amdgcn_global_load_lds((const __attribute__((address_space(1))) void*)g,
                                   (__attribute__((address_space(3))) void*)l, 4, 0, 0);
}
#define WAIT_VM0() __builtin_amdgcn_s_waitcnt(0x0F70)   // vmcnt(0)

// ---- K1: ALL bitmasks + weight packing + ghat, one dispatch.
// blocks <12544: mask/bitOp waves (R6 straight-line form, at partition HBM floor).
// blocks >=12544: aux (16 pack blocks + 1 ghat block).
__global__ __launch_bounds__(256) void k_bits_all(
    const float* __restrict__ ww, const float* __restrict__ wem,
    const float* __restrict__ d0, const float* __restrict__ d1,
    const float* __restrict__ wes, const float* __restrict__ wop,
    const float* __restrict__ nh, const float* __restrict__ Wg, const float* __restrict__ bg,
    const float* __restrict__ Wf, const float* __restrict__ Wupd, const float* __restrict__ Wo,
    u64* __restrict__ bitBig, u64* __restrict__ bitD0, u64* __restrict__ bitD1,
    u64* __restrict__ bitOp, float* __restrict__ ghat,
    uint32_t* __restrict__ pkWf, uint32_t* __restrict__ pkWu, uint32_t* __restrict__ pkWo){
  int tid = threadIdx.x;
  if (blockIdx.x >= 12544){
    int aux = blockIdx.x - 12544;
    if (aux == 16){                               // ghat
      if (tid < 128){
        int b = tid >> 6, h = tid & 63;
        float g = bg[h];
        for (int d = 0; d < 64; ++d) g += nh[b*64 + d] * Wg[d*64 + h];
        float ss = g * g;
        #pragma unroll
        for (int o = 32; o > 0; o >>= 1) ss += __shfl_xor(ss, o, 64);
        ghat[b*64 + h] = g / (sqrtf(ss) + 1e-30f);
      }
      return;
    }
    for (int k = tid; k < 1024; k += 256){        // bf16-pair weight packing
      int i = aux*1024 + k;                       // 0..16383
      const float* src; uint32_t* dst; int li;
      if (i < 8192){ src = Wf; dst = pkWf; li = i; }
      else if (i < 14336){ src = Wupd; dst = pkWu; li = i - 8192; }
      else { src = Wo; dst = pkWo; li = i - 14336; }
      int k2 = li >> 6, ln = li & 63;
      dst[li] = (uint32_t)f2b(src[(2*k2)*64 + ln]) | ((uint32_t)f2b(src[(2*k2+1)*64 + ln]) << 16);
    }
    return;
  }
  int wid = blockIdx.x*4 + (tid >> 6);
  int lane = tid & 63;
  if (wid >= 49152){                              // wes & wop -> bitOp[n][o>>6]
    int ng0 = (wid - 49152) * 8;
    #pragma unroll
    for (int i = 0; i < 8; ++i){
      int n = ng0 + i;
      float vx = wop[(size_t)n*128 + lane];
      float vy = wop[(size_t)n*128 + 64 + lane];
      float e  = wes[n];
      u64 m0 = __ballot((e != 0.f) && (vx != 0.f));
      u64 m1 = __ballot((e != 0.f) && (vy != 0.f));
      if (lane == 0) bitOp[(size_t)n*2]     = m0;
      if (lane == 1) bitOp[(size_t)n*2 + 1] = m1;
    }
    return;
  }
  const float *A, *B; u64* dst;
  if (wid < 32768){
    A = ww + (size_t)wid*1024; B = wem + (size_t)wid*1024; dst = bitBig + (size_t)wid*16;
  } else if (wid < 40960){
    size_t c = wid - 32768; A = d0 + c*1024; B = A; dst = bitD0 + c*16;
  } else {
    size_t c = wid - 40960; A = d1 + c*1024; B = A; dst = bitD1 + c*16;
  }
  const float4* ap = (const float4*)A + lane;
  const float4* bp = (const float4*)B + lane;
  float4 a0 = ap[0], a1 = ap[64], a2 = ap[128], a3 = ap[192];
  float4 b0 = bp[0], b1 = bp[64], b2 = bp[128], b3 = bp[192];
  u64 myw = 0;
#define B4(i, va, vb) { \
  u64 m0 = __ballot((va.x != 0.f) && (vb.x != 0.f)); \
  u64 m1 = __ballot((va.y != 0.f) && (vb.y != 0.f)); \
  u64 m2 = __ballot((va.z != 0.f) && (vb.z != 0.f)); \
  u64 m3 = __ballot((va.w != 0.f) && (vb.w != 0.f)); \
  if (lane == (i)*4 + 0) myw = m0; \
  if (lane == (i)*4 + 1) myw = m1; \
  if (lane == (i)*4 + 2) myw = m2; \
  if (lane == (i)*4 + 3) myw = m3; }
  B4(0, a0, b0) B4(1, a1, b1) B4(2, a2, b2) B4(3, a3, b3)
#undef B4
  if (lane < 16) dst[lane] = myw;
}

// ---- K2: dual gather from RAW w0/w1 + linear transform + l2n (k_xform eliminated).
// One wave per node row r = b*4096+n. Linearity: sum_j m[r,j]*(w[j]@W+b) = S@W + c*b.
__global__ __launch_bounds__(256) void k_gath2(
    const u64* __restrict__ bitBig, const u64* __restrict__ bitD0, const u64* __restrict__ bitD1,
    const float* __restrict__ w0, const float* __restrict__ w1,
    const float* __restrict__ Wwk, const float* __restrict__ bwk,
    const float* __restrict__ Wws, const float* __restrict__ bws,
    u16* __restrict__ wwkn, u16* __restrict__ wwsn){
  __shared__ float sWk[4096], sWs[4096];      // 32 KB
  __shared__ int q[4][256];                   // 4 KB
  __shared__ float rows[4][16][64];           // 16 KB
  int tid = threadIdx.x, lane = tid & 63, wave = tid >> 6;
  for (int i = tid; i < 1024; i += 256){
    ((float4*)sWk)[i] = ((const float4*)Wwk)[i];
    ((float4*)sWs)[i] = ((const float4*)Wws)[i];
  }
  __syncthreads();
  int wid = blockIdx.x*4 + wave;              // b*4096 + n
  int b = wid >> 12, n = wid & 4095;
  const float* w0b = w0 + (size_t)b*131072 + lane;
  const float* w1b = w1 + (size_t)b*131072 - 131072 + lane;   // valid only for j>=2048

  // ================= phase 1: big mask (word_w_k) =================
  {
    u64 word = bitBig[(size_t)wid*64 + lane];
    int c = __popcll(word);
    int pre = c;
    #pragma unroll
    for (int off = 1; off < 64; off <<= 1){
      int t = __shfl_up(pre, off, 64);
      if (lane >= off) pre += t;
    }
    int total = __shfl(pre, 63, 64);
    int base = pre - c;
    int colhi = (lane >> 2) * 256 + (lane & 3);
    u64 m = word;
    while (m){
      int p = __builtin_ctzll(m); m &= m - 1;
      q[wave][base++] = colhi + p*4;
    }
#define GP(j) ((((j) < 2048) ? w0b : w1b) + (size_t)(j)*64)
    float acc = 0.f;
    int i = 0;
    for (; i + 16 <= total; i += 16){
      int4 c0 = *(const int4*)&q[wave][i];
      int4 c1 = *(const int4*)&q[wave][i + 4];
      int4 c2 = *(const int4*)&q[wave][i + 8];
      int4 c3 = *(const int4*)&q[wave][i + 12];
      gl_lds4(GP(c0.x), &rows[wave][ 0][0]);
      gl_lds4(GP(c0.y), &rows[wave][ 1][0]);
      gl_lds4(GP(c0.z), &rows[wave][ 2][0]);
      gl_lds4(GP(c0.w), &rows[wave][ 3][0]);
      gl_lds4(GP(c1.x), &rows[wave][ 4][0]);
      gl_lds4(GP(c1.y), &rows[wave][ 5][0]);
      gl_lds4(GP(c1.z), &rows[wave][ 6][0]);
      gl_lds4(GP(c1.w), &rows[wave][ 7][0]);
      gl_lds4(GP(c2.x), &rows[wave][ 8][0]);
      gl_lds4(GP(c2.y), &rows[wave][ 9][0]);
      gl_lds4(GP(c2.z), &rows[wave][10][0]);
      gl_lds4(GP(c2.w), &rows[wave][11][0]);
      gl_lds4(GP(c3.x), &rows[wave][12][0]);
      gl_lds4(GP(c3.y), &rows[wave][13][0]);
      gl_lds4(GP(c3.z), &rows[wave][14][0]);
      gl_lds4(GP(c3.w), &rows[wave][15][0]);
      WAIT_VM0();
      float s0 = 0.f, s1 = 0.f, s2 = 0.f, s3 = 0.f;
      #pragma unroll
      for (int r = 0; r < 4; ++r){
        s0 += rows[wave][r][lane];
        s1 += rows[wave][4 + r][lane];
        s2 += rows[wave][8 + r][lane];
        s3 += rows[wave][12 + r][lane];
      }
      acc += (s0 + s1) + (s2 + s3);
    }
    for (; i < total; ++i) acc += *GP(q[wave][i]);
#undef GP
    float y = (float)total * bwk[lane];
    #pragma unroll 8
    for (int d = 0; d < 64; ++d) y += __shfl(acc, d, 64) * sWk[d*64 + lane];
    float ss = y * y;
    #pragma unroll
    for (int o = 32; o > 0; o >>= 1) ss += __shfl_xor(ss, o, 64);
    wwkn[(size_t)wid*64 + lane] = f2b(y / (sqrtf(ss) + 1e-30f));
  }

  // ================= phase 2: depend mask (word_w_s) =================
  {
    const u64* bits = (n < 2048) ? (bitD0 + ((size_t)b*2048 + n)*32)
                                 : (bitD1 + ((size_t)b*2048 + n - 2048)*32);
    const float* src = ((n < 2048) ? w0 : w1) + (size_t)b*131072 + lane;
    u64 word = (lane < 32) ? bits[lane] : 0ULL;
    int c = __popcll(word);
    int pre = c;
    #pragma unroll
    for (int off = 1; off < 64; off <<= 1){
      int t = __shfl_up(pre, off, 64);
      if (lane >= off) pre += t;
    }
    int total = __shfl(pre, 63, 64);
    int base = pre - c;
    int colhi = (lane >> 2) * 256 + (lane & 3);
    u64 m = word;
    while (m){
      int p = __builtin_ctzll(m); m &= m - 1;
      q[wave][base++] = colhi + p*4;
    }
    float acc = 0.f;
    int i = 0;
    for (; i + 16 <= total; i += 16){
      int4 c0 = *(const int4*)&q[wave][i];
      int4 c1 = *(const int4*)&q[wave][i + 4];
      int4 c2 = *(const int4*)&q[wave][i + 8];
      int4 c3 = *(const int4*)&q[wave][i + 12];
      gl_lds4(src + (size_t)c0.x*64, &rows[wave][ 0][0]);
      gl_lds4(src + (size_t)c0.y*64, &rows[wave][ 1][0]);
      gl_lds4(src + (size_t)c0.z*64, &rows[wave][ 2][0]);
      gl_lds4(src + (size_t)c0.w*64, &rows[wave][ 3][0]);
      gl_lds4(src + (size_t)c1.x*64, &rows[wave][ 4][0]);
      gl_lds4(src + (size_t)c1.y*64, &rows[wave][ 5][0]);
      gl_lds4(src + (size_t)c1.z*64, &rows[wave][ 6][0]);
      gl_lds4(src + (size_t)c1.w*64, &rows[wave][ 7][0]);
      gl_lds4(src + (size_t)c2.x*64, &rows[wave][ 8][0]);
      gl_lds4(src + (size_t)c2.y*64, &rows[wave][ 9][0]);
      gl_lds4(src + (size_t)c2.z*64, &rows[wave][10][0]);
      gl_lds4(src + (size_t)c2.w*64, &rows[wave][11][0]);
      gl_lds4(src + (size_t)c3.x*64, &rows[wave][12][0]);
      gl_lds4(src + (size_t)c3.y*64, &rows[wave][13][0]);
      gl_lds4(src + (size_t)c3.z*64, &rows[wave][14][0]);
      gl_lds4(src + (size_t)c3.w*64, &rows[wave][15][0]);
      WAIT_VM0();
      float s0 = 0.f, s1 = 0.f, s2 = 0.f, s3 = 0.f;
      #pragma unroll
      for (int r = 0; r < 4; ++r){
        s0 += rows[wave][r][lane];
        s1 += rows[wave][4 + r][lane];
        s2 += rows[wave][8 + r][lane];
        s3 += rows[wave][12 + r][lane];
      }
      acc += (s0 + s1) + (s2 + s3);
    }
    for (; i < total; ++i) acc += src[(size_t)q[wave][i]*64];
    float y = (float)total * bws[lane];
    #pragma unroll 8
    for (int d = 0; d < 64; ++d) y += __shfl(acc, d, 64) * sWs[d*64 + lane];
    float ss = y * y;
    #pragma unroll
    for (int o = 32; o > 0; o >>= 1) ss += __shfl_xor(ss, o, 64);
    wwsn[(size_t)wid*64 + lane] = f2b(y / (sqrtf(ss) + 1e-30f));
  }
}

// ---- K3: gate + update + Wo projection; weights pre-packed
__global__ __launch_bounds__(256, 2) void k_update(
    const float* __restrict__ w0, const float* __restrict__ w1,
    const float* __restrict__ gw, const float* __restrict__ ghat,
    const u16* __restrict__ wwkn, const u16* __restrict__ wwsn,
    const uint32_t* __restrict__ pkWf, const uint32_t* __restrict__ pkWu,
    const uint32_t* __restrict__ pkWo,
    const float* __restrict__ bf, const float* __restrict__ bupd, const float* __restrict__ bo,
    float* __restrict__ out, float* __restrict__ WUo){
  __shared__ uint32_t pWf[8192];    // 32 KB
  __shared__ uint32_t pWu[6144];    // 24 KB
  __shared__ uint32_t pWo[2048];    // 8 KB
  __shared__ float xsh[4][256];     // 4 KB
  int tid = threadIdx.x;
  for (int i = tid; i < 2048; i += 256) ((uint4*)pWf)[i] = ((const uint4*)pkWf)[i];
  for (int i = tid; i < 1536; i += 256) ((uint4*)pWu)[i] = ((const uint4*)pkWu)[i];
  for (int i = tid; i < 512;  i += 256) ((uint4*)pWo)[i] = ((const uint4*)pkWo)[i];
  __syncthreads();
  int lane = tid & 63, wave = tid >> 6;
  float bff = bf[lane], bup = bupd[lane], boo = bo[lane];
  float aw[4], wgv[4], wk[4], wsv[4];
  #pragma unroll
  for (int t = 0; t < 4; ++t){
    int row = blockIdx.x*4 + wave + t*2048;
    int b = row >> 12, n = row & 4095;
    aw[t] = (n < 2048) ? w0[((size_t)(b*2048 + n))*64 + lane]
                       : w1[((size_t)(b*2048 + n - 2048))*64 + lane];
    float gvv = gw[b*4096 + n];
    wgv[t] = (gvv != 0.f) ? ghat[b*64 + lane] : 0.f;
    wk[t]  = b2f(wwkn[(size_t)row*64 + lane]);
    wsv[t] = b2f(wwsn[(size_t)row*64 + lane]);
  }
  #pragma unroll
  for (int t = 0; t < 4; ++t){
    int row = blockIdx.x*4 + wave + t*2048;
    int b = row >> 12, n = row & 4095;
    xsh[wave][lane] = aw[t]; xsh[wave][64 + lane] = wgv[t];
    xsh[wave][128 + lane] = wk[t]; xsh[wave][192 + lane] = wsv[t];
    float f = bff, u = bup;
    #pragma unroll 8
    for (int k2 = 0; k2 < 32; ++k2){
      float2 xv = *(const float2*)&xsh[wave][2*k2];
      uint32_t wf = pWf[k2*64 + lane];
      f += xv.x * b2f((u16)wf) + xv.y * b2f((u16)(wf >> 16));
    }
    #pragma unroll 8
    for (int k2 = 32; k2 < 128; ++k2){
      float2 xv = *(const float2*)&xsh[wave][2*k2];
      uint32_t wf = pWf[k2*64 + lane];
      uint32_t wu = pWu[(k2 - 32)*64 + lane];
      f += xv.x * b2f((u16)wf) + xv.y * b2f((u16)(wf >> 16));
      u += xv.x * b2f((u16)wu) + xv.y * b2f((u16)(wu >> 16));
    }
    f = sigmoidf(f);
    u = fmaxf(u, 0.f);
    float wu = fmaxf(f, 0.2f) * aw[t] + (1.f - f) * u;
    out[((size_t)b*4224 + n)*64 + lane] = wu;
    float o = boo;
    #pragma unroll 8
    for (int k2 = 0; k2 < 32; ++k2){
      uint32_t wo2 = pWo[k2*64 + lane];
      o += __shfl(wu, 2*k2, 64) * b2f((u16)wo2) + __shfl(wu, 2*k2 + 1, 64) * b2f((u16)(wo2 >> 16));
    }
    WUo[(size_t)row*64 + lane] = o;
  }
}

// ---- K4: fused op aggregation + epilogue. One block per (b,o) output row.
__global__ __launch_bounds__(256) void k_opfin(
    const u64* __restrict__ bitOp, const float* __restrict__ WUo,
    const float* __restrict__ opE,
    const float* __restrict__ Wf2, const float* __restrict__ bf2,
    const float* __restrict__ Wout, const float* __restrict__ bout,
    float* __restrict__ out){
  __shared__ float sW2[8192];   // 32 KB
  __shared__ float sWo[4096];   // 16 KB
  __shared__ int q[4][96];
  __shared__ float sacc[4][64];
  __shared__ int scnt[4];
  __shared__ float xsh[128];
  int tid = threadIdx.x, lane = tid & 63, wave = tid >> 6;
  for (int i = tid; i < 2048; i += 256) ((float4*)sW2)[i] = ((const float4*)Wf2)[i];
  for (int i = tid; i < 1024; i += 256) ((float4*)sWo)[i] = ((const float4*)Wout)[i];
  int rowIdx = blockIdx.x;                      // b*128 + o
  int b = rowIdx >> 7, o = rowIdx & 127;
  int wrd = o >> 6, bit = o & 63;
  const u64* bp = bitOp + (size_t)b*8192 + (size_t)wave*2048 + wrd;
  u64 lt = (1ULL << lane) - 1ULL;
  u64 vv[16];
  #pragma unroll
  for (int it = 0; it < 16; ++it) vv[it] = bp[(size_t)(it*64 + lane)*2];
  int cnt = 0;
  #pragma unroll
  for (int it = 0; it < 16; ++it){
    bool nz = (vv[it] >> bit) & 1ULL;
    u64 m = __ballot(nz);
    if (nz) q[wave][cnt + (int)__popcll(m & lt)] = wave*1024 + it*64 + lane;
    cnt += (int)__popcll(m);
  }
  const float* Xb = WUo + (size_t)b*4096*64 + lane;
  float acc = 0.f;
  int i = 0;
  for (; i + 8 <= cnt; i += 8){
    int4 c0 = *(const int4*)&q[wave][i];
    int4 c1 = *(const int4*)&q[wave][i + 4];
    float v0 = Xb[(size_t)c0.x*64], v1 = Xb[(size_t)c0.y*64];
    float v2 = Xb[(size_t)c0.z*64], v3 = Xb[(size_t)c0.w*64];
    float v4 = Xb[(size_t)c1.x*64], v5 = Xb[(size_t)c1.y*64];
    float v6 = Xb[(size_t)c1.z*64], v7 = Xb[(size_t)c1.w*64];
    acc += ((v0 + v1) + (v2 + v3)) + ((v4 + v5) + (v6 + v7));
  }
  for (; i < cnt; ++i) acc += Xb[(size_t)q[wave][i]*64];
  sacc[wave][lane] = acc;
  if (lane == 0) scnt[wave] = cnt;
  __syncthreads();
  if (wave == 0){
    float t = sacc[0][lane] + sacc[1][lane] + sacc[2][lane] + sacc[3][lane];
    float deg = (float)(scnt[0] + scnt[1] + scnt[2] + scnt[3]);
    float wo = t / (deg + 1e-30f);
    float e  = opE[(size_t)rowIdx*64 + lane];
    xsh[lane] = e; xsh[64 + lane] = wo;
    float f = bf2[lane], u = bout[lane];
    #pragma unroll 8
    for (int k = 0; k < 128; ++k) f += xsh[k] * sW2[k*64 + lane];
    #pragma unroll 8
    for (int d = 0; d < 64; ++d)  u += xsh[64 + d] * sWo[d*64 + lane];
    f = sigmoidf(f);
    u = fmaxf(u, 0.f);
    float res = fmaxf(f, 0.2f) * e + (1.f - f) * u;
    out[((size_t)b*4224 + 4096 + o)*64 + lane] = res;
  }
}

extern "C" void kernel_launch(void* const* d_in, const int* in_sizes, int n_in,
                              void* d_out, int out_size, void* d_ws, size_t ws_size,
                              hipStream_t stream){
  const float* w0   = (const float*)d_in[0];
  const float* w1   = (const float*)d_in[1];
  const float* nh   = (const float*)d_in[2];
  const float* opE  = (const float*)d_in[3];
  const float* wes  = (const float*)d_in[4];
  const float* wem  = (const float*)d_in[5];
  const float* wop  = (const float*)d_in[6];
  const float* ww   = (const float*)d_in[7];
  const float* d0   = (const float*)d_in[8];
  const float* d1   = (const float*)d_in[9];
  const float* gw   = (const float*)d_in[10];
  const float* Wg   = (const float*)d_in[11];
  const float* bg   = (const float*)d_in[12];
  const float* Wwk  = (const float*)d_in[13];
  const float* bwk  = (const float*)d_in[14];
  const float* Wws  = (const float*)d_in[15];
  const float* bws  = (const float*)d_in[16];
  const float* Wo   = (const float*)d_in[17];
  const float* bo   = (const float*)d_in[18];
  const float* Wupd = (const float*)d_in[19];
  const float* bupd = (const float*)d_in[20];
  const float* Wf   = (const float*)d_in[21];
  const float* bf   = (const float*)d_in[22];
  const float* Wf2  = (const float*)d_in[23];
  const float* bf2  = (const float*)d_in[24];
  const float* Wout = (const float*)d_in[25];
  const float* bout = (const float*)d_in[26];

  float* ws    = (float*)d_ws;
  float* ghat  = ws;                             // 128
  uint32_t* pkWf = (uint32_t*)(ws + 128);        // 8192 u32
  uint32_t* pkWu = (uint32_t*)(ws + 8320);       // 6144 u32
  uint32_t* pkWo = (uint32_t*)(ws + 14464);      // 2048 u32
  u64*  bitBig = (u64*)(ws + 16512);             // 524288 u64 (8192 rows x 64)
  u64*  bitD0  = (u64*)(ws + 1065088);           // 131072 u64 (4096 rows x 32)
  u64*  bitD1  = (u64*)(ws + 1327232);           // 131072 u64
  u64*  bitOp  = (u64*)(ws + 1589376);           // 16384 u64
  u16*  wwkn   = (u16*)(ws + 1622144);           // 524288 u16
  u16*  wwsn   = (u16*)(ws + 1884288);           // 524288 u16
  float* WUo   = ws + 2146432;                   // 524288 f32
  float* out   = (float*)d_out;

  k_bits_all<<<12561, 256, 0, stream>>>(ww, wem, d0, d1, wes, wop, nh, Wg, bg,
                                        Wf, Wupd, Wo, bitBig, bitD0, bitD1,
                                        bitOp, ghat, pkWf, pkWu, pkWo);
  k_gath2<<<2048, 256, 0, stream>>>(bitBig, bitD0, bitD1, w0, w1,
                                    Wwk, bwk, Wws, bws, wwkn, wwsn);
  k_update<<<512, 256, 0, stream>>>(w0, w1, gw, ghat, wwkn, wwsn,
                                    pkWf, pkWu, pkWo, bf, bupd, bo, out, WUo);
  k_opfin<<<256, 256, 0, stream>>>(bitOp, WUo, opE, Wf2, bf2, Wout, bout, out);
}

// Round 10
// 443.188 us; speedup vs baseline: 1.0304x; 1.0304x over previous
//
#include <hip/hip_runtime.h>
#include <cstdint>

typedef unsigned short u16;
typedef unsigned long long u64;

__device__ __forceinline__ u16 f2b(float f){
  union { float f; uint32_t i; } v; v.f = f;
  uint32_t r = v.i + 0x7FFFu + ((v.i >> 16) & 1u);   // RNE
  return (u16)(r >> 16);
}
__device__ __forceinline__ float b2f(u16 u){
  union { uint32_t i; float f; } v; v.i = ((uint32_t)u) << 16; return v.f;
}
__device__ __forceinline__ float sigmoidf(float x){ return 1.0f / (1.0f + __expf(-x)); }

__device__ __forceinline__ void gl_lds4(const void* g, void* l){
  __builtin_amdgcn_global_load_lds((const __attribute__((address_space(1))) void*)g,
                                   (__attribute__((address_space(3))) void*)l, 4, 0, 0);
}
#define WAIT_VM0() __builtin_amdgcn_s_waitcnt(0x0F70)   // vmcnt(0)

// ---- K1: mask streaming + IN-KERNEL gathers + bitOp + weight packing + ghat.
// One wave = one 1024-col mask chunk: 8 float4 loads (HBM stream), 16 ballots,
// queue-compact nonzeros, gather w-rows from L2 via 16-deep async LDS staging,
// write bf16 partial-sum vector + count per (row,chunk). No mask bitmasks stored.
__global__ __launch_bounds__(256) void k_bits_all(
    const float* __restrict__ ww, const float* __restrict__ wem,
    const float* __restrict__ d0, const float* __restrict__ d1,
    const float* __restrict__ wes, const float* __restrict__ wop,
    const float* __restrict__ w0, const float* __restrict__ w1,
    const float* __restrict__ nh, const float* __restrict__ Wg, const float* __restrict__ bg,
    const float* __restrict__ Wf, const float* __restrict__ Wupd, const float* __restrict__ Wo,
    u16* __restrict__ psumB, int* __restrict__ pcntB,
    u16* __restrict__ psumD, int* __restrict__ pcntD,
    u64* __restrict__ bitOp, float* __restrict__ ghat,
    uint32_t* __restrict__ pkWf, uint32_t* __restrict__ pkWu, uint32_t* __restrict__ pkWo){
  __shared__ int q[4][256];
  __shared__ float rows[4][16][64];
  int tid = threadIdx.x;
  if (blockIdx.x >= 12544){
    int aux = blockIdx.x - 12544;
    if (aux == 16){                               // ghat
      if (tid < 128){
        int b = tid >> 6, h = tid & 63;
        float g = bg[h];
        for (int d = 0; d < 64; ++d) g += nh[b*64 + d] * Wg[d*64 + h];
        float ss = g * g;
        #pragma unroll
        for (int o = 32; o > 0; o >>= 1) ss += __shfl_xor(ss, o, 64);
        ghat[b*64 + h] = g / (sqrtf(ss) + 1e-30f);
      }
      return;
    }
    for (int k = tid; k < 1024; k += 256){        // bf16-pair weight packing
      int i = aux*1024 + k;                       // 0..16383
      const float* src; uint32_t* dst; int li;
      if (i < 8192){ src = Wf; dst = pkWf; li = i; }
      else if (i < 14336){ src = Wupd; dst = pkWu; li = i - 8192; }
      else { src = Wo; dst = pkWo; li = i - 14336; }
      int k2 = li >> 6, ln = li & 63;
      dst[li] = (uint32_t)f2b(src[(2*k2)*64 + ln]) | ((uint32_t)f2b(src[(2*k2+1)*64 + ln]) << 16);
    }
    return;
  }
  int wave = tid >> 6, lane = tid & 63;
  int wid = blockIdx.x*4 + wave;
  if (wid >= 49152){                              // wes & wop -> bitOp[n][o>>6]
    int ng0 = (wid - 49152) * 8;
    #pragma unroll
    for (int i = 0; i < 8; ++i){
      int n = ng0 + i;
      float vx = wop[(size_t)n*128 + lane];
      float vy = wop[(size_t)n*128 + 64 + lane];
      float e  = wes[n];
      u64 m0 = __ballot((e != 0.f) && (vx != 0.f));
      u64 m1 = __ballot((e != 0.f) && (vy != 0.f));
      if (lane == 0) bitOp[(size_t)n*2]     = m0;
      if (lane == 1) bitOp[(size_t)n*2 + 1] = m1;
    }
    return;
  }
  // ---- mask chunk setup
  const float *A, *B;
  const float *srcA, *srcB;     // gather bases (+lane); j<thresh -> srcA else srcB
  int jbase, thresh;
  u16* ps; int* pc;
  if (wid < 32768){                               // big: row = b*4096+n, 4 chunks
    int row = wid >> 2, chunk = wid & 3;
    int b = row >> 12;
    A = ww  + (size_t)row*4096 + chunk*1024;
    B = wem + (size_t)row*4096 + chunk*1024;
    srcA = w0 + (size_t)b*131072 + lane;
    srcB = w1 + (size_t)b*131072 - 131072 + lane;
    jbase = chunk*1024; thresh = 2048;
    ps = psumB + (size_t)wid*64; pc = pcntB + wid;
  } else {                                        // dep: rowp<4096 -> d0, else d1
    int idx = wid - 32768;
    int rowp = idx >> 1, chunk = idx & 1;
    if (rowp < 4096){
      int b = rowp >> 11;
      A = d0 + (size_t)rowp*2048 + chunk*1024;
      srcA = w0 + (size_t)b*131072 + lane;
    } else {
      int rr = rowp - 4096, b = rr >> 11;
      A = d1 + (size_t)rr*2048 + chunk*1024;
      srcA = w1 + (size_t)b*131072 + lane;
    }
    B = A; srcB = srcA;
    jbase = chunk*1024; thresh = 4096;            // never hits srcB
    ps = psumD + (size_t)idx*64; pc = pcntD + idx;
  }
  // ---- stream 4 KB(+4 KB) of mask, ballot to 16 words (lanes 0..15)
  const float4* ap = (const float4*)A + lane;
  const float4* bp = (const float4*)B + lane;
  float4 a0 = ap[0], a1 = ap[64], a2 = ap[128], a3 = ap[192];
  float4 b0 = bp[0], b1 = bp[64], b2 = bp[128], b3 = bp[192];
  u64 myw = 0;
#define B4(i, va, vb) { \
  u64 m0 = __ballot((va.x != 0.f) && (vb.x != 0.f)); \
  u64 m1 = __ballot((va.y != 0.f) && (vb.y != 0.f)); \
  u64 m2 = __ballot((va.z != 0.f) && (vb.z != 0.f)); \
  u64 m3 = __ballot((va.w != 0.f) && (vb.w != 0.f)); \
  if (lane == (i)*4 + 0) myw = m0; \
  if (lane == (i)*4 + 1) myw = m1; \
  if (lane == (i)*4 + 2) myw = m2; \
  if (lane == (i)*4 + 3) myw = m3; }
  B4(0, a0, b0) B4(1, a1, b1) B4(2, a2, b2) B4(3, a3, b3)
#undef B4
  // ---- compact nonzero chunk-cols into LDS queue
  int c = __popcll(myw);
  int pre = c;
  #pragma unroll
  for (int off = 1; off < 64; off <<= 1){
    int t = __shfl_up(pre, off, 64);
    if (lane >= off) pre += t;
  }
  int total = __shfl(pre, 63, 64);
  int base = pre - c;
  int colhi = (lane >> 2) * 256 + (lane & 3);
  u64 m = myw;
  while (m){
    int p = __builtin_ctzll(m); m &= m - 1;
    q[wave][base++] = colhi + p*4;
  }
  // ---- gather w-rows (L2-resident), 16-deep async batches
#define GPJ(qv) (((jbase + (qv)) < thresh ? srcA : srcB) + (size_t)(jbase + (qv))*64)
  float acc = 0.f;
  int i = 0;
  for (; i + 16 <= total; i += 16){
    int4 c0 = *(const int4*)&q[wave][i];
    int4 c1 = *(const int4*)&q[wave][i + 4];
    int4 c2 = *(const int4*)&q[wave][i + 8];
    int4 c3 = *(const int4*)&q[wave][i + 12];
    gl_lds4(GPJ(c0.x), &rows[wave][ 0][0]);
    gl_lds4(GPJ(c0.y), &rows[wave][ 1][0]);
    gl_lds4(GPJ(c0.z), &rows[wave][ 2][0]);
    gl_lds4(GPJ(c0.w), &rows[wave][ 3][0]);
    gl_lds4(GPJ(c1.x), &rows[wave][ 4][0]);
    gl_lds4(GPJ(c1.y), &rows[wave][ 5][0]);
    gl_lds4(GPJ(c1.z), &rows[wave][ 6][0]);
    gl_lds4(GPJ(c1.w), &rows[wave][ 7][0]);
    gl_lds4(GPJ(c2.x), &rows[wave][ 8][0]);
    gl_lds4(GPJ(c2.y), &rows[wave][ 9][0]);
    gl_lds4(GPJ(c2.z), &rows[wave][10][0]);
    gl_lds4(GPJ(c2.w), &rows[wave][11][0]);
    gl_lds4(GPJ(c3.x), &rows[wave][12][0]);
    gl_lds4(GPJ(c3.y), &rows[wave][13][0]);
    gl_lds4(GPJ(c3.z), &rows[wave][14][0]);
    gl_lds4(GPJ(c3.w), &rows[wave][15][0]);
    WAIT_VM0();
    float s0 = 0.f, s1 = 0.f, s2 = 0.f, s3 = 0.f;
    #pragma unroll
    for (int r = 0; r < 4; ++r){
      s0 += rows[wave][r][lane];
      s1 += rows[wave][4 + r][lane];
      s2 += rows[wave][8 + r][lane];
      s3 += rows[wave][12 + r][lane];
    }
    acc += (s0 + s1) + (s2 + s3);
  }
  for (; i < total; ++i) acc += *GPJ(q[wave][i]);
#undef GPJ
  ps[lane] = f2b(acc);
  if (lane == 0) pc[0] = total;
}

// ---- K2: combine partials + linear transform + c*bias + l2n (deg cancels under l2n)
__global__ __launch_bounds__(256) void k_fin(
    const u16* __restrict__ psumB, const int* __restrict__ pcntB,
    const u16* __restrict__ psumD, const int* __restrict__ pcntD,
    const float* __restrict__ Wwk, const float* __restrict__ bwk,
    const float* __restrict__ Wws, const float* __restrict__ bws,
    u16* __restrict__ wwkn, u16* __restrict__ wwsn){
  __shared__ float sWk[4096], sWs[4096];
  int tid = threadIdx.x, lane = tid & 63, wave = tid >> 6;
  for (int i = tid; i < 1024; i += 256){
    ((float4*)sWk)[i] = ((const float4*)Wwk)[i];
    ((float4*)sWs)[i] = ((const float4*)Wws)[i];
  }
  __syncthreads();
  int wid = blockIdx.x*4 + wave;
  float S; float y; const float* sW; u16* outp; size_t oidx;
  if (wid < 8192){                                // big rows (word_w_k)
    S = b2f(psumB[((size_t)wid*4 + 0)*64 + lane]) + b2f(psumB[((size_t)wid*4 + 1)*64 + lane])
      + b2f(psumB[((size_t)wid*4 + 2)*64 + lane]) + b2f(psumB[((size_t)wid*4 + 3)*64 + lane]);
    int T = pcntB[wid*4] + pcntB[wid*4 + 1] + pcntB[wid*4 + 2] + pcntB[wid*4 + 3];
    y = (float)T * bwk[lane]; sW = sWk; outp = wwkn; oidx = wid;
  } else {                                        // dep rows (word_w_s)
    int rp = wid - 8192;
    S = b2f(psumD[((size_t)rp*2 + 0)*64 + lane]) + b2f(psumD[((size_t)rp*2 + 1)*64 + lane]);
    int T = pcntD[rp*2] + pcntD[rp*2 + 1];
    y = (float)T * bws[lane]; sW = sWs; outp = wwsn;
    int b, n;
    if (rp < 4096){ b = rp >> 11; n = rp & 2047; }
    else { int rr = rp - 4096; b = rr >> 11; n = 2048 + (rr & 2047); }
    oidx = (size_t)b*4096 + n;
  }
  #pragma unroll 8
  for (int d = 0; d < 64; ++d) y += __shfl(S, d, 64) * sW[d*64 + lane];
  float ss = y * y;
  #pragma unroll
  for (int o = 32; o > 0; o >>= 1) ss += __shfl_xor(ss, o, 64);
  outp[oidx*64 + lane] = f2b(y / (sqrtf(ss) + 1e-30f));
}

// ---- K3: gate + update + Wo projection; weights pre-packed (R8 verbatim)
__global__ __launch_bounds__(256, 2) void k_update(
    const float* __restrict__ w0, const float* __restrict__ w1,
    const float* __restrict__ gw, const float* __restrict__ ghat,
    const u16* __restrict__ wwkn, const u16* __restrict__ wwsn,
    const uint32_t* __restrict__ pkWf, const uint32_t* __restrict__ pkWu,
    const uint32_t* __restrict__ pkWo,
    const float* __restrict__ bf, const float* __restrict__ bupd, const float* __restrict__ bo,
    float* __restrict__ out, float* __restrict__ WUo){
  __shared__ uint32_t pWf[8192];    // 32 KB
  __shared__ uint32_t pWu[6144];    // 24 KB
  __shared__ uint32_t pWo[2048];    // 8 KB
  __shared__ float xsh[4][256];     // 4 KB
  int tid = threadIdx.x;
  for (int i = tid; i < 2048; i += 256) ((uint4*)pWf)[i] = ((const uint4*)pkWf)[i];
  for (int i = tid; i < 1536; i += 256) ((uint4*)pWu)[i] = ((const uint4*)pkWu)[i];
  for (int i = tid; i < 512;  i += 256) ((uint4*)pWo)[i] = ((const uint4*)pkWo)[i];
  __syncthreads();
  int lane = tid & 63, wave = tid >> 6;
  float bff = bf[lane], bup = bupd[lane], boo = bo[lane];
  float aw[4], wgv[4], wk[4], wsv[4];
  #pragma unroll
  for (int t = 0; t < 4; ++t){
    int row = blockIdx.x*4 + wave + t*2048;
    int b = row >> 12, n = row & 4095;
    aw[t] = (n < 2048) ? w0[((size_t)(b*2048 + n))*64 + lane]
                       : w1[((size_t)(b*2048 + n - 2048))*64 + lane];
    float gvv = gw[b*4096 + n];
    wgv[t] = (gvv != 0.f) ? ghat[b*64 + lane] : 0.f;
    wk[t]  = b2f(wwkn[(size_t)row*64 + lane]);
    wsv[t] = b2f(wwsn[(size_t)row*64 + lane]);
  }
  #pragma unroll
  for (int t = 0; t < 4; ++t){
    int row = blockIdx.x*4 + wave + t*2048;
    int b = row >> 12, n = row & 4095;
    xsh[wave][lane] = aw[t]; xsh[wave][64 + lane] = wgv[t];
    xsh[wave][128 + lane] = wk[t]; xsh[wave][192 + lane] = wsv[t];
    float f = bff, u = bup;
    #pragma unroll 8
    for (int k2 = 0; k2 < 32; ++k2){
      float2 xv = *(const float2*)&xsh[wave][2*k2];
      uint32_t wf = pWf[k2*64 + lane];
      f += xv.x * b2f((u16)wf) + xv.y * b2f((u16)(wf >> 16));
    }
    #pragma unroll 8
    for (int k2 = 32; k2 < 128; ++k2){
      float2 xv = *(const float2*)&xsh[wave][2*k2];
      uint32_t wf = pWf[k2*64 + lane];
      uint32_t wu = pWu[(k2 - 32)*64 + lane];
      f += xv.x * b2f((u16)wf) + xv.y * b2f((u16)(wf >> 16));
      u += xv.x * b2f((u16)wu) + xv.y * b2f((u16)(wu >> 16));
    }
    f = sigmoidf(f);
    u = fmaxf(u, 0.f);
    float wu = fmaxf(f, 0.2f) * aw[t] + (1.f - f) * u;
    out[((size_t)b*4224 + n)*64 + lane] = wu;
    float o = boo;
    #pragma unroll 8
    for (int k2 = 0; k2 < 32; ++k2){
      uint32_t wo2 = pWo[k2*64 + lane];
      o += __shfl(wu, 2*k2, 64) * b2f((u16)wo2) + __shfl(wu, 2*k2 + 1, 64) * b2f((u16)(wo2 >> 16));
    }
    WUo[(size_t)row*64 + lane] = o;
  }
}

// ---- K4: fused op aggregation + epilogue (R8 verbatim). One block per (b,o).
__global__ __launch_bounds__(256) void k_opfin(
    const u64* __restrict__ bitOp, const float* __restrict__ WUo,
    const float* __restrict__ opE,
    const float* __restrict__ Wf2, const float* __restrict__ bf2,
    const float* __restrict__ Wout, const float* __restrict__ bout,
    float* __restrict__ out){
  __shared__ float sW2[8192];   // 32 KB
  __shared__ float sWo[4096];   // 16 KB
  __shared__ int q[4][96];
  __shared__ float sacc[4][64];
  __shared__ int scnt[4];
  __shared__ float xsh[128];
  int tid = threadIdx.x, lane = tid & 63, wave = tid >> 6;
  for (int i = tid; i < 2048; i += 256) ((float4*)sW2)[i] = ((const float4*)Wf2)[i];
  for (int i = tid; i < 1024; i += 256) ((float4*)sWo)[i] = ((const float4*)Wout)[i];
  int rowIdx = blockIdx.x;                      // b*128 + o
  int b = rowIdx >> 7, o = rowIdx & 127;
  int wrd = o >> 6, bit = o & 63;
  const u64* bp = bitOp + (size_t)b*8192 + (size_t)wave*2048 + wrd;
  u64 lt = (1ULL << lane) - 1ULL;
  u64 vv[16];
  #pragma unroll
  for (int it = 0; it < 16; ++it) vv[it] = bp[(size_t)(it*64 + lane)*2];
  int cnt = 0;
  #pragma unroll
  for (int it = 0; it < 16; ++it){
    bool nz = (vv[it] >> bit) & 1ULL;
    u64 m = __ballot(nz);
    if (nz) q[wave][cnt + (int)__popcll(m & lt)] = wave*1024 + it*64 + lane;
    cnt += (int)__popcll(m);
  }
  const float* Xb = WUo + (size_t)b*4096*64 + lane;
  float acc = 0.f;
  int i = 0;
  for (; i + 8 <= cnt; i += 8){
    int4 c0 = *(const int4*)&q[wave][i];
    int4 c1 = *(const int4*)&q[wave][i + 4];
    float v0 = Xb[(size_t)c0.x*64], v1 = Xb[(size_t)c0.y*64];
    float v2 = Xb[(size_t)c0.z*64], v3 = Xb[(size_t)c0.w*64];
    float v4 = Xb[(size_t)c1.x*64], v5 = Xb[(size_t)c1.y*64];
    float v6 = Xb[(size_t)c1.z*64], v7 = Xb[(size_t)c1.w*64];
    acc += ((v0 + v1) + (v2 + v3)) + ((v4 + v5) + (v6 + v7));
  }
  for (; i < cnt; ++i) acc += Xb[(size_t)q[wave][i]*64];
  sacc[wave][lane] = acc;
  if (lane == 0) scnt[wave] = cnt;
  __syncthreads();
  if (wave == 0){
    float t = sacc[0][lane] + sacc[1][lane] + sacc[2][lane] + sacc[3][lane];
    float deg = (float)(scnt[0] + scnt[1] + scnt[2] + scnt[3]);
    float wo = t / (deg + 1e-30f);
    float e  = opE[(size_t)rowIdx*64 + lane];
    xsh[lane] = e; xsh[64 + lane] = wo;
    float f = bf2[lane], u = bout[lane];
    #pragma unroll 8
    for (int k = 0; k < 128; ++k) f += xsh[k] * sW2[k*64 + lane];
    #pragma unroll 8
    for (int d = 0; d < 64; ++d)  u += xsh[64 + d] * sWo[d*64 + lane];
    f = sigmoidf(f);
    u = fmaxf(u, 0.f);
    float res = fmaxf(f, 0.2f) * e + (1.f - f) * u;
    out[((size_t)b*4224 + 4096 + o)*64 + lane] = res;
  }
}

extern "C" void kernel_launch(void* const* d_in, const int* in_sizes, int n_in,
                              void* d_out, int out_size, void* d_ws, size_t ws_size,
                              hipStream_t stream){
  const float* w0   = (const float*)d_in[0];
  const float* w1   = (const float*)d_in[1];
  const float* nh   = (const float*)d_in[2];
  const float* opE  = (const float*)d_in[3];
  const float* wes  = (const float*)d_in[4];
  const float* wem  = (const float*)d_in[5];
  const float* wop  = (const float*)d_in[6];
  const float* ww   = (const float*)d_in[7];
  const float* d0   = (const float*)d_in[8];
  const float* d1   = (const float*)d_in[9];
  const float* gw   = (const float*)d_in[10];
  const float* Wg   = (const float*)d_in[11];
  const float* bg   = (const float*)d_in[12];
  const float* Wwk  = (const float*)d_in[13];
  const float* bwk  = (const float*)d_in[14];
  const float* Wws  = (const float*)d_in[15];
  const float* bws  = (const float*)d_in[16];
  const float* Wo   = (const float*)d_in[17];
  const float* bo   = (const float*)d_in[18];
  const float* Wupd = (const float*)d_in[19];
  const float* bupd = (const float*)d_in[20];
  const float* Wf   = (const float*)d_in[21];
  const float* bf   = (const float*)d_in[22];
  const float* Wf2  = (const float*)d_in[23];
  const float* bf2  = (const float*)d_in[24];
  const float* Wout = (const float*)d_in[25];
  const float* bout = (const float*)d_in[26];

  float* ws    = (float*)d_ws;
  float* ghat  = ws;                             // 128
  uint32_t* pkWf = (uint32_t*)(ws + 128);        // 8192 u32
  uint32_t* pkWu = (uint32_t*)(ws + 8320);       // 6144 u32
  uint32_t* pkWo = (uint32_t*)(ws + 14464);      // 2048 u32
  u64*  bitOp  = (u64*)(ws + 16512);             // 16384 u64 (32768 f32)
  u16*  psumB  = (u16*)(ws + 49280);             // 32768 chunks x 64 u16 (1048576 f32)
  int*  pcntB  = (int*)(ws + 1097856);           // 32768 int
  u16*  psumD  = (u16*)(ws + 1130624);           // 16384 chunks x 64 u16 (524288 f32)
  int*  pcntD  = (int*)(ws + 1654912);           // 16384 int
  u16*  wwkn   = (u16*)(ws + 1671296);           // 524288 u16 (262144 f32)
  u16*  wwsn   = (u16*)(ws + 1933440);           // 524288 u16
  float* WUo   = ws + 2195584;                   // 524288 f32
  float* out   = (float*)d_out;

  k_bits_all<<<12561, 256, 0, stream>>>(ww, wem, d0, d1, wes, wop, w0, w1,
                                        nh, Wg, bg, Wf, Wupd, Wo,
                                        psumB, pcntB, psumD, pcntD,
                                        bitOp, ghat, pkWf, pkWu, pkWo);
  k_fin<<<4096, 256, 0, stream>>>(psumB, pcntB, psumD, pcntD,
                                  Wwk, bwk, Wws, bws, wwkn, wwsn);
  k_update<<<512, 256, 0, stream>>>(w0, w1, gw, ghat, wwkn, wwsn,
                                    pkWf, pkWu, pkWo, bf, bupd, bo, out, WUo);
  k_opfin<<<256, 256, 0, stream>>>(bitOp, WUo, opE, Wf2, bf2, Wout, bout, out);
}